// Round 15
// baseline (207.274 us; speedup 1.0000x reference)
//
#include <hip/hip_runtime.h>
#include <math.h>
#include <string.h>

// piSGC R15: merge-path (edge-balanced) spmv.
//  - each 20-lane group owns ~CE contiguous csr edges: binary-search start[]
//    for first node, process all nodes starting in the span. Fixes the
//    Poisson-degree wave imbalance behind R14's 63% occupancy.
//  - bucket_base fused into bucket_csr (redundant 256-wide LDS scan per block)
//  - rest identical to R14 (scan-free reservation build, packed 4B csr,
//    csr_scale pre-fold, NT output store)

#define ALPHA  0.05f
#define SCALE  0.475f   // (1 - ALPHA) / NUM_LAYERS
#define FDIM   64
#define CDIM   40
#define NPAD   131072
#define CHUNK  8192
#define BCAP   10240
#define CE     64        // edges per merge-path group
#define SRCMASK 0x1FFFFu

__device__ __forceinline__ unsigned short f2bf(float f) {
    unsigned u = __float_as_uint(f);
    unsigned r = (u + 0x7FFFu + ((u >> 16) & 1u)) >> 16;   // round-nearest-even
    return (unsigned short)r;
}
__device__ __forceinline__ float bfLo(unsigned u) { return __uint_as_float(u << 16); }
__device__ __forceinline__ float bfHi(unsigned u) { return __uint_as_float(u & 0xffff0000u); }
__device__ __forceinline__ float wUnpack(unsigned v) {
    return __uint_as_float((v >> 17) << 16);
}

// ---- part_scatter: hist chunk -> reserve ranges -> scatter packed payload ----
__global__ __launch_bounds__(1024) void part_scatter(
        const int* __restrict__ row, const int* __restrict__ col,
        const float* __restrict__ ea, int* __restrict__ alloc,
        int2* __restrict__ ppay, int E) {
    __shared__ unsigned h[256];
    __shared__ unsigned offs[256];
    int tid = threadIdx.x, blk = blockIdx.x;
    if (tid < 256) h[tid] = 0;
    __syncthreads();
    int base = blk * CHUNK;
    int end  = min(base + CHUNK, E);
    for (int e = base + tid; e < end; e += 1024)
        atomicAdd(&h[col[e] >> 9], 1u);
    __syncthreads();
    if (tid < 256) {
        unsigned hc = h[tid];
        unsigned r = hc ? (unsigned)atomicAdd(&alloc[tid], (int)hc) : 0u;
        offs[tid] = (unsigned)(tid * BCAP) + r;
    }
    __syncthreads();
    for (int e = base + tid; e < end; e += 1024) {
        int c = col[e];
        int bin = c >> 9;
        unsigned p = atomicAdd(&offs[bin], 1u);
        if (p < (unsigned)((bin + 1) * BCAP))
            ppay[p] = make_int2(row[e] | ((c & 511) << 20), __float_as_int(ea[e]));
    }
}

// ---- bucket_csr: per-bucket finalize (base scan fused); octant ordering ----
__global__ __launch_bounds__(256) void bucket_csr(
        const int2* __restrict__ ppay, const int* __restrict__ alloc,
        int* __restrict__ start, unsigned* __restrict__ csr,
        float* __restrict__ dis, int N) {
    __shared__ unsigned cnt8[512][8];
    __shared__ unsigned ps[256], exc[512];
    __shared__ float sdeg[512];
    __shared__ int sAll[256];
    int tid = threadIdx.x, k = blockIdx.x;

    // fused bucket_base: scan alloc -> this bucket's e0
    sAll[tid] = min(alloc[tid], BCAP);
    __syncthreads();
    int v = sAll[tid];
    for (int off = 1; off < 256; off <<= 1) {
        int t = (tid >= off) ? sAll[tid - off] : 0;
        __syncthreads();
        sAll[tid] += t;
        __syncthreads();
    }
    int e0  = sAll[k] - min(alloc[k], BCAP);
    int cnt = min(alloc[k], BCAP);
    (void)v;
    const int2* src = ppay + (size_t)k * BCAP;

    for (int i = tid; i < 4096; i += 256) ((unsigned*)cnt8)[i] = 0;
    sdeg[tid] = 0.0f; sdeg[tid + 256] = 0.0f;
    __syncthreads();

    for (int j = tid; j < cnt; j += 256) {
        int2 pay = src[j];
        int c = (pay.x >> 20) & 511;
        atomicAdd(&cnt8[c][(pay.x & 0xFFFFF) >> 14], 1u);
        atomicAdd(&sdeg[c], __int_as_float(pay.y));
    }
    __syncthreads();

    int c0 = 2 * tid, c1 = 2 * tid + 1;
    unsigned t0 = 0, t1 = 0;
    #pragma unroll
    for (int o = 0; o < 8; ++o) { t0 += cnt8[c0][o]; t1 += cnt8[c1][o]; }
    unsigned pair = t0 + t1;
    ps[tid] = pair;
    __syncthreads();
    for (int off = 1; off < 256; off <<= 1) {
        unsigned t = (tid >= off) ? ps[tid - off] : 0;
        __syncthreads();
        ps[tid] += t;
        __syncthreads();
    }
    unsigned pexc = ps[tid] - pair;
    exc[c0] = pexc;
    exc[c1] = pexc + t0;
    unsigned b = pexc;
    #pragma unroll
    for (int o = 0; o < 8; ++o) { unsigned t = cnt8[c0][o]; cnt8[c0][o] = b; b += t; }
    b = pexc + t0;
    #pragma unroll
    for (int o = 0; o < 8; ++o) { unsigned t = cnt8[c1][o]; cnt8[c1][o] = b; b += t; }
    __syncthreads();

    #pragma unroll
    for (int i = tid; i < 512; i += 256) {
        int g = k * 512 + i;
        if (g <= N) start[g] = e0 + (int)exc[i];
        if (g < N) {
            float d = sdeg[i];
            dis[g] = (d > 0.0f) ? rsqrtf(fmaxf(d, 1e-12f)) : 0.0f;
        }
    }

    for (int j = tid; j < cnt; j += 256) {
        int2 pay = src[j];
        int c    = (pay.x >> 20) & 511;
        int srcn = pay.x & 0xFFFFF;
        unsigned p = atomicAdd(&cnt8[c][srcn >> 14], 1u);
        unsigned wbf = (unsigned)f2bf(__int_as_float(pay.y));   // ea >= 0
        csr[e0 + p] = (unsigned)srcn | (wbf << 17);
    }
}

// ---- fold dis[src] into packed csr weight ----
__global__ void csr_scale_kernel(unsigned* __restrict__ csr,
                                 const float* __restrict__ dis, int E) {
    int stride = gridDim.x * blockDim.x;
    for (int e = blockIdx.x * blockDim.x + threadIdx.x; e < E; e += stride) {
        unsigned v = csr[e];
        unsigned src = v & SRCMASK;
        float w = wUnpack(v) * dis[src];
        csr[e] = src | ((unsigned)f2bf(w) << 17);
    }
}

// ---- y = x @ W, bf16 packed. 4 threads/node x 10 outputs ----
__global__ __launch_bounds__(256) void lin_kernel(
        const float* __restrict__ x, const float* __restrict__ W,
        unsigned* __restrict__ ybf, int N) {
    __shared__ float sWt[CDIM][FDIM + 4];
    for (int i = threadIdx.x; i < FDIM * CDIM; i += 256) {
        int k = i / CDIM, c = i - k * CDIM;
        sWt[c][k] = W[i];
    }
    __syncthreads();

    int t = threadIdx.x;
    int node = blockIdx.x * 64 + (t >> 2);
    if (node >= N) return;
    int cs = (t & 3) * 10;

    float acc[10];
    #pragma unroll
    for (int i = 0; i < 10; ++i) acc[i] = 0.0f;

    const float4* xr = (const float4*)(x + (size_t)node * FDIM);
    #pragma unroll
    for (int k4 = 0; k4 < FDIM / 4; ++k4) {
        float4 v = xr[k4];
        #pragma unroll
        for (int i = 0; i < 10; ++i) {
            const float4 w = *(const float4*)&sWt[cs + i][k4 * 4];
            acc[i] = fmaf(v.x, w.x, fmaf(v.y, w.y, fmaf(v.z, w.z, fmaf(v.w, w.w, acc[i]))));
        }
    }

    unsigned* yr = ybf + (size_t)node * (CDIM / 2) + (t & 3) * 5;
    #pragma unroll
    for (int k = 0; k < 5; ++k)
        yr[k] = (unsigned)f2bf(acc[2 * k]) | ((unsigned)f2bf(acc[2 * k + 1]) << 16);
}

// ---- merge-path spmv1: each group owns csr[lo, lo+CE) ----
__global__ __launch_bounds__(256) void spmv_mp(
        const unsigned* __restrict__ gin, const int* __restrict__ start,
        const unsigned* __restrict__ csr, const float* __restrict__ dis,
        unsigned* __restrict__ gout, int N, int E, int G) {
    int lane = threadIdx.x & 63;
    int wid  = threadIdx.x >> 6;
    int grp  = lane / 20;
    int grel = lane - grp * 20;
    int g = blockIdx.x * 12 + wid * 3 + grp;
    bool act = (grp < 3) && (g < G);
    int lo  = act ? g * CE : (E + 2);
    int hiR = min(lo + CE, E + 1);

    // lower_bound over start[0..N] for lo (group-uniform; L2-hot)
    int a = 0, b = N;
    while (a < b) { int mid = (a + b) >> 1; if (start[mid] < lo) a = mid + 1; else b = mid; }

    int n = a;
    while (n < N && start[n] < hiR) {
        int e0 = start[n], e1 = start[n + 1];
        float aL0 = 0, aL1 = 0, aL2 = 0, aL3 = 0;
        float aH0 = 0, aH1 = 0, aH2 = 0, aH3 = 0;
        int j = e0;
        for (; j + 7 < e1; j += 8) {
            unsigned v0 = csr[j],     v1 = csr[j + 1], v2 = csr[j + 2], v3 = csr[j + 3];
            unsigned v4 = csr[j + 4], v5 = csr[j + 5], v6 = csr[j + 6], v7 = csr[j + 7];
            unsigned u0 = gin[(size_t)(v0 & SRCMASK) * 20 + grel];
            unsigned u1 = gin[(size_t)(v1 & SRCMASK) * 20 + grel];
            unsigned u2 = gin[(size_t)(v2 & SRCMASK) * 20 + grel];
            unsigned u3 = gin[(size_t)(v3 & SRCMASK) * 20 + grel];
            unsigned u4 = gin[(size_t)(v4 & SRCMASK) * 20 + grel];
            unsigned u5 = gin[(size_t)(v5 & SRCMASK) * 20 + grel];
            unsigned u6 = gin[(size_t)(v6 & SRCMASK) * 20 + grel];
            unsigned u7 = gin[(size_t)(v7 & SRCMASK) * 20 + grel];
            float w0 = wUnpack(v0), w1 = wUnpack(v1), w2 = wUnpack(v2), w3 = wUnpack(v3);
            float w4 = wUnpack(v4), w5 = wUnpack(v5), w6 = wUnpack(v6), w7 = wUnpack(v7);
            aL0 = fmaf(w0, bfLo(u0), aL0); aH0 = fmaf(w0, bfHi(u0), aH0);
            aL1 = fmaf(w1, bfLo(u1), aL1); aH1 = fmaf(w1, bfHi(u1), aH1);
            aL2 = fmaf(w2, bfLo(u2), aL2); aH2 = fmaf(w2, bfHi(u2), aH2);
            aL3 = fmaf(w3, bfLo(u3), aL3); aH3 = fmaf(w3, bfHi(u3), aH3);
            aL0 = fmaf(w4, bfLo(u4), aL0); aH0 = fmaf(w4, bfHi(u4), aH0);
            aL1 = fmaf(w5, bfLo(u5), aL1); aH1 = fmaf(w5, bfHi(u5), aH1);
            aL2 = fmaf(w6, bfLo(u6), aL2); aH2 = fmaf(w6, bfHi(u6), aH2);
            aL3 = fmaf(w7, bfLo(u7), aL3); aH3 = fmaf(w7, bfHi(u7), aH3);
        }
        for (; j < e1; ++j) {
            unsigned v = csr[j];
            unsigned u = gin[(size_t)(v & SRCMASK) * 20 + grel];
            float w = wUnpack(v);
            aL0 = fmaf(w, bfLo(u), aL0); aH0 = fmaf(w, bfHi(u), aH0);
        }
        float dn = dis[n];
        float lov = dn * ((aL0 + aL1) + (aL2 + aL3));
        float hiv = dn * ((aH0 + aH1) + (aH2 + aH3));
        gout[(size_t)n * 20 + grel] = (unsigned)f2bf(lov) | ((unsigned)f2bf(hiv) << 16);
        ++n;
    }
}

// ---- merge-path conv2 + log_softmax epilogue ----
__global__ __launch_bounds__(256) void spmv_final_mp(
        const unsigned* __restrict__ g1, const unsigned* __restrict__ y,
        const float* __restrict__ bias, const int* __restrict__ start,
        const unsigned* __restrict__ csr, const float* __restrict__ dis,
        float* __restrict__ out, int N, int E, int G) {
    int lane = threadIdx.x & 63;
    int wid  = threadIdx.x >> 6;
    int grp  = lane / 20;
    int grel = lane - grp * 20;
    int g = blockIdx.x * 12 + wid * 3 + grp;
    bool act = (grp < 3) && (g < G);
    int lo  = act ? g * CE : (E + 2);
    int hiR = min(lo + CE, E + 1);

    int a = 0, b = N;
    while (a < b) { int mid = (a + b) >> 1; if (start[mid] < lo) a = mid + 1; else b = mid; }

    int n = a;
    while (n < N && start[n] < hiR) {
        int e0 = start[n], e1 = start[n + 1];
        float aL0 = 0, aL1 = 0, aL2 = 0, aL3 = 0;
        float aH0 = 0, aH1 = 0, aH2 = 0, aH3 = 0;
        int j = e0;
        for (; j + 7 < e1; j += 8) {
            unsigned v0 = csr[j],     v1 = csr[j + 1], v2 = csr[j + 2], v3 = csr[j + 3];
            unsigned v4 = csr[j + 4], v5 = csr[j + 5], v6 = csr[j + 6], v7 = csr[j + 7];
            unsigned u0 = g1[(size_t)(v0 & SRCMASK) * 20 + grel];
            unsigned u1 = g1[(size_t)(v1 & SRCMASK) * 20 + grel];
            unsigned u2 = g1[(size_t)(v2 & SRCMASK) * 20 + grel];
            unsigned u3 = g1[(size_t)(v3 & SRCMASK) * 20 + grel];
            unsigned u4 = g1[(size_t)(v4 & SRCMASK) * 20 + grel];
            unsigned u5 = g1[(size_t)(v5 & SRCMASK) * 20 + grel];
            unsigned u6 = g1[(size_t)(v6 & SRCMASK) * 20 + grel];
            unsigned u7 = g1[(size_t)(v7 & SRCMASK) * 20 + grel];
            float w0 = wUnpack(v0), w1 = wUnpack(v1), w2 = wUnpack(v2), w3 = wUnpack(v3);
            float w4 = wUnpack(v4), w5 = wUnpack(v5), w6 = wUnpack(v6), w7 = wUnpack(v7);
            aL0 = fmaf(w0, bfLo(u0), aL0); aH0 = fmaf(w0, bfHi(u0), aH0);
            aL1 = fmaf(w1, bfLo(u1), aL1); aH1 = fmaf(w1, bfHi(u1), aH1);
            aL2 = fmaf(w2, bfLo(u2), aL2); aH2 = fmaf(w2, bfHi(u2), aH2);
            aL3 = fmaf(w3, bfLo(u3), aL3); aH3 = fmaf(w3, bfHi(u3), aH3);
            aL0 = fmaf(w4, bfLo(u4), aL0); aH0 = fmaf(w4, bfHi(u4), aH0);
            aL1 = fmaf(w5, bfLo(u5), aL1); aH1 = fmaf(w5, bfHi(u5), aH1);
            aL2 = fmaf(w6, bfLo(u6), aL2); aH2 = fmaf(w6, bfHi(u6), aH2);
            aL3 = fmaf(w7, bfLo(u7), aL3); aH3 = fmaf(w7, bfHi(u7), aH3);
        }
        for (; j < e1; ++j) {
            unsigned v = csr[j];
            unsigned u = g1[(size_t)(v & SRCMASK) * 20 + grel];
            float w = wUnpack(v);
            aL0 = fmaf(w, bfLo(u), aL0); aH0 = fmaf(w, bfHi(u), aH0);
        }

        float dn  = dis[n];
        float g2L = dn * ((aL0 + aL1) + (aL2 + aL3));
        float g2H = dn * ((aH0 + aH1) + (aH2 + aH3));
        unsigned yu = y[(size_t)n * 20 + grel];
        unsigned gu = g1[(size_t)n * 20 + grel];
        float2 bv = *(const float2*)&bias[2 * grel];
        float logitL = fmaf(ALPHA, bfLo(yu), fmaf(SCALE, bfLo(gu) + g2L, bv.x));
        float logitH = fmaf(ALPHA, bfHi(yu), fmaf(SCALE, bfHi(gu) + g2H, bv.y));

        float m = fmaxf(logitL, logitH);
        #pragma unroll
        for (int off = 16; off; off >>= 1) {
            float o = __shfl(m, lane + off);
            if (grel + off < 20) m = fmaxf(m, o);
        }
        m = __shfl(m, grp * 20);

        float ex = expf(logitL - m) + expf(logitH - m);
        #pragma unroll
        for (int off = 16; off; off >>= 1) {
            float o = __shfl(ex, lane + off);
            if (grel + off < 20) ex += o;
        }
        ex = __shfl(ex, grp * 20);

        float lse = m + logf(ex);
        float2 o;
        o.x = logitL - lse;
        o.y = logitH - lse;
        double dv;
        memcpy(&dv, &o, 8);
        __builtin_nontemporal_store(dv, (double*)&out[(size_t)n * CDIM + 2 * grel]);
        ++n;
    }
}

extern "C" void kernel_launch(void* const* d_in, const int* in_sizes, int n_in,
                              void* d_out, int out_size, void* d_ws, size_t ws_size,
                              hipStream_t stream) {
    const float* x  = (const float*)d_in[0];   // [N,64]
    const float* ea = (const float*)d_in[1];   // [E]
    const float* W  = (const float*)d_in[2];   // [64,40]
    const float* b  = (const float*)d_in[3];   // [40]
    const int*   ei = (const int*)d_in[4];     // [2,E]: row then col

    const int N = in_sizes[0] / FDIM;
    const int E = in_sizes[1];
    const int* row = ei;
    const int* col = ei + E;

    const int NBLK = (E + CHUNK - 1) / CHUNK;
    const int G    = (E + CE) / CE;            // ceil((E+1)/CE) merge-path groups

    // workspace layout (4-byte words; every used region fully written each call)
    int*   startp = (int*)d_ws;                   // NPAD
    float* dis    = (float*)(startp + NPAD);      // NPAD
    int*   alloc  = (int*)(dis + NPAD);           // 1024 (256 used)
    int2*  ppay   = (int2*)(alloc + 1024);        // 256*BCAP int2 (~21 MB)
    unsigned* csr = (unsigned*)(ppay + 256 * BCAP); // E packed dwords
    unsigned* g1bf = csr + E;                     // N*20
    unsigned* ybf  = (unsigned*)ppay;             // aliases ppay (dead after bucket_csr)

    hipMemsetAsync(alloc, 0, 256 * sizeof(int), stream);

    part_scatter<<<NBLK, 1024, 0, stream>>>(row, col, ea, alloc, ppay, E);
    bucket_csr  <<<256, 256, 0, stream>>>(ppay, alloc, startp, csr, dis, N);
    csr_scale_kernel<<<2048, 256, 0, stream>>>(csr, dis, E);
    lin_kernel  <<<(N + 63) / 64, 256, 0, stream>>>(x, W, ybf, N);

    int mp_blocks = (G + 11) / 12;
    spmv_mp      <<<mp_blocks, 256, 0, stream>>>(ybf, startp, csr, dis, g1bf, N, E, G);
    spmv_final_mp<<<mp_blocks, 256, 0, stream>>>(g1bf, ybf, b, startp, csr, dis,
                                                 (float*)d_out, N, E, G);
}

// Round 16
// 181.114 us; speedup vs baseline: 1.1444x; 1.1444x over previous
//
#include <hip/hip_runtime.h>
#include <math.h>
#include <string.h>

// piSGC R16: R14 structure (best: 157.5us), with
//  - spmv groups own 4 consecutive nodes (NPG=4): max-of-3-Poisson wave
//    imbalance drops ~35% -> ~13% (R15's span-ownership rewrite REVERTED)
//  - bucket_base fused into bucket_csr (kept from R15)
//  - scan-free reservation build, packed 4B csr, csr_scale pre-fold, NT store

#define ALPHA  0.05f
#define SCALE  0.475f   // (1 - ALPHA) / NUM_LAYERS
#define FDIM   64
#define CDIM   40
#define NPAD   131072
#define CHUNK  8192
#define BCAP   10240
#define NPG    4         // nodes per 20-lane group
#define SRCMASK 0x1FFFFu

__device__ __forceinline__ unsigned short f2bf(float f) {
    unsigned u = __float_as_uint(f);
    unsigned r = (u + 0x7FFFu + ((u >> 16) & 1u)) >> 16;   // round-nearest-even
    return (unsigned short)r;
}
__device__ __forceinline__ float bfLo(unsigned u) { return __uint_as_float(u << 16); }
__device__ __forceinline__ float bfHi(unsigned u) { return __uint_as_float(u & 0xffff0000u); }
__device__ __forceinline__ float wUnpack(unsigned v) {
    return __uint_as_float((v >> 17) << 16);
}

// ---- part_scatter: hist chunk -> reserve ranges -> scatter packed payload ----
__global__ __launch_bounds__(1024) void part_scatter(
        const int* __restrict__ row, const int* __restrict__ col,
        const float* __restrict__ ea, int* __restrict__ alloc,
        int2* __restrict__ ppay, int E) {
    __shared__ unsigned h[256];
    __shared__ unsigned offs[256];
    int tid = threadIdx.x, blk = blockIdx.x;
    if (tid < 256) h[tid] = 0;
    __syncthreads();
    int base = blk * CHUNK;
    int end  = min(base + CHUNK, E);
    for (int e = base + tid; e < end; e += 1024)
        atomicAdd(&h[col[e] >> 9], 1u);
    __syncthreads();
    if (tid < 256) {
        unsigned hc = h[tid];
        unsigned r = hc ? (unsigned)atomicAdd(&alloc[tid], (int)hc) : 0u;
        offs[tid] = (unsigned)(tid * BCAP) + r;
    }
    __syncthreads();
    for (int e = base + tid; e < end; e += 1024) {
        int c = col[e];
        int bin = c >> 9;
        unsigned p = atomicAdd(&offs[bin], 1u);
        if (p < (unsigned)((bin + 1) * BCAP))
            ppay[p] = make_int2(row[e] | ((c & 511) << 20), __float_as_int(ea[e]));
    }
}

// ---- bucket_csr: per-bucket finalize (base scan fused); octant ordering ----
__global__ __launch_bounds__(256) void bucket_csr(
        const int2* __restrict__ ppay, const int* __restrict__ alloc,
        int* __restrict__ start, unsigned* __restrict__ csr,
        float* __restrict__ dis, int N) {
    __shared__ unsigned cnt8[512][8];
    __shared__ unsigned ps[256], exc[512];
    __shared__ float sdeg[512];
    __shared__ int sAll[256];
    int tid = threadIdx.x, k = blockIdx.x;

    // fused bucket_base: scan alloc -> this bucket's e0
    int myCnt = min(alloc[tid], BCAP);
    sAll[tid] = myCnt;
    __syncthreads();
    for (int off = 1; off < 256; off <<= 1) {
        int t = (tid >= off) ? sAll[tid - off] : 0;
        __syncthreads();
        sAll[tid] += t;
        __syncthreads();
    }
    int cnt = min(alloc[k], BCAP);
    int e0  = sAll[k] - cnt;
    const int2* src = ppay + (size_t)k * BCAP;

    for (int i = tid; i < 4096; i += 256) ((unsigned*)cnt8)[i] = 0;
    sdeg[tid] = 0.0f; sdeg[tid + 256] = 0.0f;
    __syncthreads();

    for (int j = tid; j < cnt; j += 256) {
        int2 pay = src[j];
        int c = (pay.x >> 20) & 511;
        atomicAdd(&cnt8[c][(pay.x & 0xFFFFF) >> 14], 1u);
        atomicAdd(&sdeg[c], __int_as_float(pay.y));
    }
    __syncthreads();

    int c0 = 2 * tid, c1 = 2 * tid + 1;
    unsigned t0 = 0, t1 = 0;
    #pragma unroll
    for (int o = 0; o < 8; ++o) { t0 += cnt8[c0][o]; t1 += cnt8[c1][o]; }
    unsigned pair = t0 + t1;
    ps[tid] = pair;
    __syncthreads();
    for (int off = 1; off < 256; off <<= 1) {
        unsigned t = (tid >= off) ? ps[tid - off] : 0;
        __syncthreads();
        ps[tid] += t;
        __syncthreads();
    }
    unsigned pexc = ps[tid] - pair;
    exc[c0] = pexc;
    exc[c1] = pexc + t0;
    unsigned b = pexc;
    #pragma unroll
    for (int o = 0; o < 8; ++o) { unsigned t = cnt8[c0][o]; cnt8[c0][o] = b; b += t; }
    b = pexc + t0;
    #pragma unroll
    for (int o = 0; o < 8; ++o) { unsigned t = cnt8[c1][o]; cnt8[c1][o] = b; b += t; }
    __syncthreads();

    #pragma unroll
    for (int i = tid; i < 512; i += 256) {
        int g = k * 512 + i;
        if (g <= N) start[g] = e0 + (int)exc[i];
        if (g < N) {
            float d = sdeg[i];
            dis[g] = (d > 0.0f) ? rsqrtf(fmaxf(d, 1e-12f)) : 0.0f;
        }
    }

    for (int j = tid; j < cnt; j += 256) {
        int2 pay = src[j];
        int c    = (pay.x >> 20) & 511;
        int srcn = pay.x & 0xFFFFF;
        unsigned p = atomicAdd(&cnt8[c][srcn >> 14], 1u);
        unsigned wbf = (unsigned)f2bf(__int_as_float(pay.y));   // ea >= 0
        csr[e0 + p] = (unsigned)srcn | (wbf << 17);
    }
}

// ---- fold dis[src] into packed csr weight ----
__global__ void csr_scale_kernel(unsigned* __restrict__ csr,
                                 const float* __restrict__ dis, int E) {
    int stride = gridDim.x * blockDim.x;
    for (int e = blockIdx.x * blockDim.x + threadIdx.x; e < E; e += stride) {
        unsigned v = csr[e];
        unsigned src = v & SRCMASK;
        float w = wUnpack(v) * dis[src];
        csr[e] = src | ((unsigned)f2bf(w) << 17);
    }
}

// ---- y = x @ W, bf16 packed. 4 threads/node x 10 outputs ----
__global__ __launch_bounds__(256) void lin_kernel(
        const float* __restrict__ x, const float* __restrict__ W,
        unsigned* __restrict__ ybf, int N) {
    __shared__ float sWt[CDIM][FDIM + 4];
    for (int i = threadIdx.x; i < FDIM * CDIM; i += 256) {
        int k = i / CDIM, c = i - k * CDIM;
        sWt[c][k] = W[i];
    }
    __syncthreads();

    int t = threadIdx.x;
    int node = blockIdx.x * 64 + (t >> 2);
    if (node >= N) return;
    int cs = (t & 3) * 10;

    float acc[10];
    #pragma unroll
    for (int i = 0; i < 10; ++i) acc[i] = 0.0f;

    const float4* xr = (const float4*)(x + (size_t)node * FDIM);
    #pragma unroll
    for (int k4 = 0; k4 < FDIM / 4; ++k4) {
        float4 v = xr[k4];
        #pragma unroll
        for (int i = 0; i < 10; ++i) {
            const float4 w = *(const float4*)&sWt[cs + i][k4 * 4];
            acc[i] = fmaf(v.x, w.x, fmaf(v.y, w.y, fmaf(v.z, w.z, fmaf(v.w, w.w, acc[i]))));
        }
    }

    unsigned* yr = ybf + (size_t)node * (CDIM / 2) + (t & 3) * 5;
    #pragma unroll
    for (int k = 0; k < 5; ++k)
        yr[k] = (unsigned)f2bf(acc[2 * k]) | ((unsigned)f2bf(acc[2 * k + 1]) << 16);
}

// ---- spmv1: group of 20 lanes processes NPG consecutive nodes ----
__global__ __launch_bounds__(256) void spmv_kernel(
        const unsigned* __restrict__ gin, const int* __restrict__ start,
        const unsigned* __restrict__ csr, const float* __restrict__ dis,
        unsigned* __restrict__ gout, int N) {
    int lane = threadIdx.x & 63;
    int wid  = threadIdx.x >> 6;
    int grp  = lane / 20;
    int grel = lane - grp * 20;
    if (grp >= 3) return;
    int nbase = (blockIdx.x * 12 + wid * 3 + grp) * NPG;

    for (int k = 0; k < NPG; ++k) {
        int node = nbase + k;
        if (node >= N) break;
        int e0 = start[node], e1 = start[node + 1];
        float aL0 = 0, aL1 = 0, aL2 = 0, aL3 = 0;
        float aH0 = 0, aH1 = 0, aH2 = 0, aH3 = 0;
        int j = e0;
        for (; j + 7 < e1; j += 8) {
            unsigned v0 = csr[j],     v1 = csr[j + 1], v2 = csr[j + 2], v3 = csr[j + 3];
            unsigned v4 = csr[j + 4], v5 = csr[j + 5], v6 = csr[j + 6], v7 = csr[j + 7];
            unsigned u0 = gin[(size_t)(v0 & SRCMASK) * 20 + grel];
            unsigned u1 = gin[(size_t)(v1 & SRCMASK) * 20 + grel];
            unsigned u2 = gin[(size_t)(v2 & SRCMASK) * 20 + grel];
            unsigned u3 = gin[(size_t)(v3 & SRCMASK) * 20 + grel];
            unsigned u4 = gin[(size_t)(v4 & SRCMASK) * 20 + grel];
            unsigned u5 = gin[(size_t)(v5 & SRCMASK) * 20 + grel];
            unsigned u6 = gin[(size_t)(v6 & SRCMASK) * 20 + grel];
            unsigned u7 = gin[(size_t)(v7 & SRCMASK) * 20 + grel];
            float w0 = wUnpack(v0), w1 = wUnpack(v1), w2 = wUnpack(v2), w3 = wUnpack(v3);
            float w4 = wUnpack(v4), w5 = wUnpack(v5), w6 = wUnpack(v6), w7 = wUnpack(v7);
            aL0 = fmaf(w0, bfLo(u0), aL0); aH0 = fmaf(w0, bfHi(u0), aH0);
            aL1 = fmaf(w1, bfLo(u1), aL1); aH1 = fmaf(w1, bfHi(u1), aH1);
            aL2 = fmaf(w2, bfLo(u2), aL2); aH2 = fmaf(w2, bfHi(u2), aH2);
            aL3 = fmaf(w3, bfLo(u3), aL3); aH3 = fmaf(w3, bfHi(u3), aH3);
            aL0 = fmaf(w4, bfLo(u4), aL0); aH0 = fmaf(w4, bfHi(u4), aH0);
            aL1 = fmaf(w5, bfLo(u5), aL1); aH1 = fmaf(w5, bfHi(u5), aH1);
            aL2 = fmaf(w6, bfLo(u6), aL2); aH2 = fmaf(w6, bfHi(u6), aH2);
            aL3 = fmaf(w7, bfLo(u7), aL3); aH3 = fmaf(w7, bfHi(u7), aH3);
        }
        for (; j < e1; ++j) {
            unsigned v = csr[j];
            unsigned u = gin[(size_t)(v & SRCMASK) * 20 + grel];
            float w = wUnpack(v);
            aL0 = fmaf(w, bfLo(u), aL0); aH0 = fmaf(w, bfHi(u), aH0);
        }
        float dn = dis[node];
        float lo = dn * ((aL0 + aL1) + (aL2 + aL3));
        float hi = dn * ((aH0 + aH1) + (aH2 + aH3));
        gout[(size_t)node * 20 + grel] = (unsigned)f2bf(lo) | ((unsigned)f2bf(hi) << 16);
    }
}

// ---- conv2 + log_softmax epilogue; NPG nodes per group ----
__global__ __launch_bounds__(256) void spmv_final_kernel(
        const unsigned* __restrict__ g1, const unsigned* __restrict__ y,
        const float* __restrict__ bias, const int* __restrict__ start,
        const unsigned* __restrict__ csr, const float* __restrict__ dis,
        float* __restrict__ out, int N) {
    int lane = threadIdx.x & 63;
    int wid  = threadIdx.x >> 6;
    int grp  = lane / 20;
    int grel = lane - grp * 20;
    int nbase = (blockIdx.x * 12 + wid * 3 + grp) * NPG;
    bool actg = (grp < 3);

    for (int k = 0; k < NPG; ++k) {
        int node = nbase + k;
        bool act = actg && (node < N);
        int e0 = 0, e1 = 0;
        if (act) { e0 = start[node]; e1 = start[node + 1]; }

        float aL0 = 0, aL1 = 0, aL2 = 0, aL3 = 0;
        float aH0 = 0, aH1 = 0, aH2 = 0, aH3 = 0;
        int j = e0;
        for (; j + 7 < e1; j += 8) {
            unsigned v0 = csr[j],     v1 = csr[j + 1], v2 = csr[j + 2], v3 = csr[j + 3];
            unsigned v4 = csr[j + 4], v5 = csr[j + 5], v6 = csr[j + 6], v7 = csr[j + 7];
            unsigned u0 = g1[(size_t)(v0 & SRCMASK) * 20 + grel];
            unsigned u1 = g1[(size_t)(v1 & SRCMASK) * 20 + grel];
            unsigned u2 = g1[(size_t)(v2 & SRCMASK) * 20 + grel];
            unsigned u3 = g1[(size_t)(v3 & SRCMASK) * 20 + grel];
            unsigned u4 = g1[(size_t)(v4 & SRCMASK) * 20 + grel];
            unsigned u5 = g1[(size_t)(v5 & SRCMASK) * 20 + grel];
            unsigned u6 = g1[(size_t)(v6 & SRCMASK) * 20 + grel];
            unsigned u7 = g1[(size_t)(v7 & SRCMASK) * 20 + grel];
            float w0 = wUnpack(v0), w1 = wUnpack(v1), w2 = wUnpack(v2), w3 = wUnpack(v3);
            float w4 = wUnpack(v4), w5 = wUnpack(v5), w6 = wUnpack(v6), w7 = wUnpack(v7);
            aL0 = fmaf(w0, bfLo(u0), aL0); aH0 = fmaf(w0, bfHi(u0), aH0);
            aL1 = fmaf(w1, bfLo(u1), aL1); aH1 = fmaf(w1, bfHi(u1), aH1);
            aL2 = fmaf(w2, bfLo(u2), aL2); aH2 = fmaf(w2, bfHi(u2), aH2);
            aL3 = fmaf(w3, bfLo(u3), aL3); aH3 = fmaf(w3, bfHi(u3), aH3);
            aL0 = fmaf(w4, bfLo(u4), aL0); aH0 = fmaf(w4, bfHi(u4), aH0);
            aL1 = fmaf(w5, bfLo(u5), aL1); aH1 = fmaf(w5, bfHi(u5), aH1);
            aL2 = fmaf(w6, bfLo(u6), aL2); aH2 = fmaf(w6, bfHi(u6), aH2);
            aL3 = fmaf(w7, bfLo(u7), aL3); aH3 = fmaf(w7, bfHi(u7), aH3);
        }
        for (; j < e1; ++j) {
            unsigned v = csr[j];
            unsigned u = g1[(size_t)(v & SRCMASK) * 20 + grel];
            float w = wUnpack(v);
            aL0 = fmaf(w, bfLo(u), aL0); aH0 = fmaf(w, bfHi(u), aH0);
        }

        float logitL = 0.0f, logitH = 0.0f;
        if (act) {
            float dn  = dis[node];
            float g2L = dn * ((aL0 + aL1) + (aL2 + aL3));
            float g2H = dn * ((aH0 + aH1) + (aH2 + aH3));
            unsigned yu = y[(size_t)node * 20 + grel];
            unsigned gu = g1[(size_t)node * 20 + grel];
            float2 bv = *(const float2*)&bias[2 * grel];
            logitL = fmaf(ALPHA, bfLo(yu), fmaf(SCALE, bfLo(gu) + g2L, bv.x));
            logitH = fmaf(ALPHA, bfHi(yu), fmaf(SCALE, bfHi(gu) + g2H, bv.y));
        }

        float m = act ? fmaxf(logitL, logitH) : -INFINITY;
        #pragma unroll
        for (int off = 16; off; off >>= 1) {
            float o = __shfl(m, lane + off);
            if (grel + off < 20) m = fmaxf(m, o);
        }
        m = __shfl(m, grp * 20);

        float ex = act ? (expf(logitL - m) + expf(logitH - m)) : 0.0f;
        #pragma unroll
        for (int off = 16; off; off >>= 1) {
            float o = __shfl(ex, lane + off);
            if (grel + off < 20) ex += o;
        }
        ex = __shfl(ex, grp * 20);

        if (act) {
            float lse = m + logf(ex);
            float2 o;
            o.x = logitL - lse;
            o.y = logitH - lse;
            double dv;
            memcpy(&dv, &o, 8);
            __builtin_nontemporal_store(dv, (double*)&out[(size_t)node * CDIM + 2 * grel]);
        }
    }
}

extern "C" void kernel_launch(void* const* d_in, const int* in_sizes, int n_in,
                              void* d_out, int out_size, void* d_ws, size_t ws_size,
                              hipStream_t stream) {
    const float* x  = (const float*)d_in[0];   // [N,64]
    const float* ea = (const float*)d_in[1];   // [E]
    const float* W  = (const float*)d_in[2];   // [64,40]
    const float* b  = (const float*)d_in[3];   // [40]
    const int*   ei = (const int*)d_in[4];     // [2,E]: row then col

    const int N = in_sizes[0] / FDIM;
    const int E = in_sizes[1];
    const int* row = ei;
    const int* col = ei + E;

    const int NBLK = (E + CHUNK - 1) / CHUNK;

    // workspace layout (4-byte words; every used region fully written each call)
    int*   startp = (int*)d_ws;                   // NPAD
    float* dis    = (float*)(startp + NPAD);      // NPAD
    int*   alloc  = (int*)(dis + NPAD);           // 1024 (256 used)
    int2*  ppay   = (int2*)(alloc + 1024);        // 256*BCAP int2 (~21 MB)
    unsigned* csr = (unsigned*)(ppay + 256 * BCAP); // E packed dwords
    unsigned* g1bf = csr + E;                     // N*20
    unsigned* ybf  = (unsigned*)ppay;             // aliases ppay (dead after bucket_csr)

    hipMemsetAsync(alloc, 0, 256 * sizeof(int), stream);

    part_scatter<<<NBLK, 1024, 0, stream>>>(row, col, ea, alloc, ppay, E);
    bucket_csr  <<<256, 256, 0, stream>>>(ppay, alloc, startp, csr, dis, N);
    csr_scale_kernel<<<2048, 256, 0, stream>>>(csr, dis, E);
    lin_kernel  <<<(N + 63) / 64, 256, 0, stream>>>(x, W, ybf, N);

    int groups = (N + NPG - 1) / NPG;
    int spmv_blocks = (groups + 11) / 12;
    spmv_kernel      <<<spmv_blocks, 256, 0, stream>>>(ybf, startp, csr, dis, g1bf, N);
    spmv_final_kernel<<<spmv_blocks, 256, 0, stream>>>(g1bf, ybf, b, startp, csr, dis,
                                                       (float*)d_out, N);
}

// Round 17
// 145.923 us; speedup vs baseline: 1.4204x; 1.2412x over previous
//
#include <hip/hip_runtime.h>
#include <math.h>
#include <string.h>

// piSGC R17: R14 structure + 10-lane/node spmv (6 nodes per wave, uint2 gathers).
//  - R16's NPG serialization REVERTED (killed inter-node MLP, grid 4x smaller)
//  - spmv: lane owns 4 features (8B uint2 load); 6 independent node streams
//    per wave -> 2x outstanding gathers vs R14's 3x20-lane layout
//  - bucket_base fused into bucket_csr (kept; safe)
//  - scan-free reservation build, packed 4B csr, csr_scale pre-fold, NT store

#define ALPHA  0.05f
#define SCALE  0.475f   // (1 - ALPHA) / NUM_LAYERS
#define FDIM   64
#define CDIM   40
#define NPAD   131072
#define CHUNK  8192
#define BCAP   10240
#define SRCMASK 0x1FFFFu

__device__ __forceinline__ unsigned short f2bf(float f) {
    unsigned u = __float_as_uint(f);
    unsigned r = (u + 0x7FFFu + ((u >> 16) & 1u)) >> 16;   // round-nearest-even
    return (unsigned short)r;
}
__device__ __forceinline__ float bfLo(unsigned u) { return __uint_as_float(u << 16); }
__device__ __forceinline__ float bfHi(unsigned u) { return __uint_as_float(u & 0xffff0000u); }
__device__ __forceinline__ float wUnpack(unsigned v) {
    return __uint_as_float((v >> 17) << 16);
}

// ---- part_scatter: hist chunk -> reserve ranges -> scatter packed payload ----
__global__ __launch_bounds__(1024) void part_scatter(
        const int* __restrict__ row, const int* __restrict__ col,
        const float* __restrict__ ea, int* __restrict__ alloc,
        int2* __restrict__ ppay, int E) {
    __shared__ unsigned h[256];
    __shared__ unsigned offs[256];
    int tid = threadIdx.x, blk = blockIdx.x;
    if (tid < 256) h[tid] = 0;
    __syncthreads();
    int base = blk * CHUNK;
    int end  = min(base + CHUNK, E);
    for (int e = base + tid; e < end; e += 1024)
        atomicAdd(&h[col[e] >> 9], 1u);
    __syncthreads();
    if (tid < 256) {
        unsigned hc = h[tid];
        unsigned r = hc ? (unsigned)atomicAdd(&alloc[tid], (int)hc) : 0u;
        offs[tid] = (unsigned)(tid * BCAP) + r;
    }
    __syncthreads();
    for (int e = base + tid; e < end; e += 1024) {
        int c = col[e];
        int bin = c >> 9;
        unsigned p = atomicAdd(&offs[bin], 1u);
        if (p < (unsigned)((bin + 1) * BCAP))
            ppay[p] = make_int2(row[e] | ((c & 511) << 20), __float_as_int(ea[e]));
    }
}

// ---- bucket_csr: per-bucket finalize (base scan fused); octant ordering ----
__global__ __launch_bounds__(256) void bucket_csr(
        const int2* __restrict__ ppay, const int* __restrict__ alloc,
        int* __restrict__ start, unsigned* __restrict__ csr,
        float* __restrict__ dis, int N) {
    __shared__ unsigned cnt8[512][8];
    __shared__ unsigned ps[256], exc[512];
    __shared__ float sdeg[512];
    __shared__ int sAll[256];
    int tid = threadIdx.x, k = blockIdx.x;

    // fused bucket_base: scan alloc -> this bucket's e0
    int myCnt = min(alloc[tid], BCAP);
    sAll[tid] = myCnt;
    __syncthreads();
    for (int off = 1; off < 256; off <<= 1) {
        int t = (tid >= off) ? sAll[tid - off] : 0;
        __syncthreads();
        sAll[tid] += t;
        __syncthreads();
    }
    int cnt = min(alloc[k], BCAP);
    int e0  = sAll[k] - cnt;
    const int2* src = ppay + (size_t)k * BCAP;

    for (int i = tid; i < 4096; i += 256) ((unsigned*)cnt8)[i] = 0;
    sdeg[tid] = 0.0f; sdeg[tid + 256] = 0.0f;
    __syncthreads();

    for (int j = tid; j < cnt; j += 256) {
        int2 pay = src[j];
        int c = (pay.x >> 20) & 511;
        atomicAdd(&cnt8[c][(pay.x & 0xFFFFF) >> 14], 1u);
        atomicAdd(&sdeg[c], __int_as_float(pay.y));
    }
    __syncthreads();

    int c0 = 2 * tid, c1 = 2 * tid + 1;
    unsigned t0 = 0, t1 = 0;
    #pragma unroll
    for (int o = 0; o < 8; ++o) { t0 += cnt8[c0][o]; t1 += cnt8[c1][o]; }
    unsigned pair = t0 + t1;
    ps[tid] = pair;
    __syncthreads();
    for (int off = 1; off < 256; off <<= 1) {
        unsigned t = (tid >= off) ? ps[tid - off] : 0;
        __syncthreads();
        ps[tid] += t;
        __syncthreads();
    }
    unsigned pexc = ps[tid] - pair;
    exc[c0] = pexc;
    exc[c1] = pexc + t0;
    unsigned b = pexc;
    #pragma unroll
    for (int o = 0; o < 8; ++o) { unsigned t = cnt8[c0][o]; cnt8[c0][o] = b; b += t; }
    b = pexc + t0;
    #pragma unroll
    for (int o = 0; o < 8; ++o) { unsigned t = cnt8[c1][o]; cnt8[c1][o] = b; b += t; }
    __syncthreads();

    #pragma unroll
    for (int i = tid; i < 512; i += 256) {
        int g = k * 512 + i;
        if (g <= N) start[g] = e0 + (int)exc[i];
        if (g < N) {
            float d = sdeg[i];
            dis[g] = (d > 0.0f) ? rsqrtf(fmaxf(d, 1e-12f)) : 0.0f;
        }
    }

    for (int j = tid; j < cnt; j += 256) {
        int2 pay = src[j];
        int c    = (pay.x >> 20) & 511;
        int srcn = pay.x & 0xFFFFF;
        unsigned p = atomicAdd(&cnt8[c][srcn >> 14], 1u);
        unsigned wbf = (unsigned)f2bf(__int_as_float(pay.y));   // ea >= 0
        csr[e0 + p] = (unsigned)srcn | (wbf << 17);
    }
}

// ---- fold dis[src] into packed csr weight ----
__global__ void csr_scale_kernel(unsigned* __restrict__ csr,
                                 const float* __restrict__ dis, int E) {
    int stride = gridDim.x * blockDim.x;
    for (int e = blockIdx.x * blockDim.x + threadIdx.x; e < E; e += stride) {
        unsigned v = csr[e];
        unsigned src = v & SRCMASK;
        float w = wUnpack(v) * dis[src];
        csr[e] = src | ((unsigned)f2bf(w) << 17);
    }
}

// ---- y = x @ W, bf16 packed. 4 threads/node x 10 outputs ----
__global__ __launch_bounds__(256) void lin_kernel(
        const float* __restrict__ x, const float* __restrict__ W,
        unsigned* __restrict__ ybf, int N) {
    __shared__ float sWt[CDIM][FDIM + 4];
    for (int i = threadIdx.x; i < FDIM * CDIM; i += 256) {
        int k = i / CDIM, c = i - k * CDIM;
        sWt[c][k] = W[i];
    }
    __syncthreads();

    int t = threadIdx.x;
    int node = blockIdx.x * 64 + (t >> 2);
    if (node >= N) return;
    int cs = (t & 3) * 10;

    float acc[10];
    #pragma unroll
    for (int i = 0; i < 10; ++i) acc[i] = 0.0f;

    const float4* xr = (const float4*)(x + (size_t)node * FDIM);
    #pragma unroll
    for (int k4 = 0; k4 < FDIM / 4; ++k4) {
        float4 v = xr[k4];
        #pragma unroll
        for (int i = 0; i < 10; ++i) {
            const float4 w = *(const float4*)&sWt[cs + i][k4 * 4];
            acc[i] = fmaf(v.x, w.x, fmaf(v.y, w.y, fmaf(v.z, w.z, fmaf(v.w, w.w, acc[i]))));
        }
    }

    unsigned* yr = ybf + (size_t)node * (CDIM / 2) + (t & 3) * 5;
    #pragma unroll
    for (int k = 0; k < 5; ++k)
        yr[k] = (unsigned)f2bf(acc[2 * k]) | ((unsigned)f2bf(acc[2 * k + 1]) << 16);
}

// ---- spmv1: 10 lanes/node (uint2 = 4 features), 6 nodes per wave ----
__global__ __launch_bounds__(256) void spmv_kernel(
        const unsigned* __restrict__ gin, const int* __restrict__ start,
        const unsigned* __restrict__ csr, const float* __restrict__ dis,
        unsigned* __restrict__ gout, int N) {
    int lane = threadIdx.x & 63;
    int wid  = threadIdx.x >> 6;
    int grp  = lane / 10;            // 0..5 active; lanes 60-63 idle
    int grel = lane - grp * 10;
    int node = blockIdx.x * 24 + wid * 6 + grp;
    bool act = (grp < 6) && (node < N);

    int e0 = 0, e1 = 0;
    if (act) { e0 = start[node]; e1 = start[node + 1]; }
    const uint2* gin2 = (const uint2*)gin;

    float a0 = 0, a1 = 0, a2 = 0, a3 = 0;
    float b0 = 0, b1 = 0, b2 = 0, b3 = 0;
    int j = e0;
    for (; j + 7 < e1; j += 8) {
        unsigned v0 = csr[j],     v1 = csr[j + 1], v2 = csr[j + 2], v3 = csr[j + 3];
        unsigned v4 = csr[j + 4], v5 = csr[j + 5], v6 = csr[j + 6], v7 = csr[j + 7];
        uint2 u0 = gin2[(size_t)(v0 & SRCMASK) * 10 + grel];
        uint2 u1 = gin2[(size_t)(v1 & SRCMASK) * 10 + grel];
        uint2 u2 = gin2[(size_t)(v2 & SRCMASK) * 10 + grel];
        uint2 u3 = gin2[(size_t)(v3 & SRCMASK) * 10 + grel];
        uint2 u4 = gin2[(size_t)(v4 & SRCMASK) * 10 + grel];
        uint2 u5 = gin2[(size_t)(v5 & SRCMASK) * 10 + grel];
        uint2 u6 = gin2[(size_t)(v6 & SRCMASK) * 10 + grel];
        uint2 u7 = gin2[(size_t)(v7 & SRCMASK) * 10 + grel];
        float w0 = wUnpack(v0), w1 = wUnpack(v1), w2 = wUnpack(v2), w3 = wUnpack(v3);
        float w4 = wUnpack(v4), w5 = wUnpack(v5), w6 = wUnpack(v6), w7 = wUnpack(v7);
        a0 = fmaf(w0, bfLo(u0.x), a0); a1 = fmaf(w0, bfHi(u0.x), a1);
        a2 = fmaf(w0, bfLo(u0.y), a2); a3 = fmaf(w0, bfHi(u0.y), a3);
        b0 = fmaf(w1, bfLo(u1.x), b0); b1 = fmaf(w1, bfHi(u1.x), b1);
        b2 = fmaf(w1, bfLo(u1.y), b2); b3 = fmaf(w1, bfHi(u1.y), b3);
        a0 = fmaf(w2, bfLo(u2.x), a0); a1 = fmaf(w2, bfHi(u2.x), a1);
        a2 = fmaf(w2, bfLo(u2.y), a2); a3 = fmaf(w2, bfHi(u2.y), a3);
        b0 = fmaf(w3, bfLo(u3.x), b0); b1 = fmaf(w3, bfHi(u3.x), b1);
        b2 = fmaf(w3, bfLo(u3.y), b2); b3 = fmaf(w3, bfHi(u3.y), b3);
        a0 = fmaf(w4, bfLo(u4.x), a0); a1 = fmaf(w4, bfHi(u4.x), a1);
        a2 = fmaf(w4, bfLo(u4.y), a2); a3 = fmaf(w4, bfHi(u4.y), a3);
        b0 = fmaf(w5, bfLo(u5.x), b0); b1 = fmaf(w5, bfHi(u5.x), b1);
        b2 = fmaf(w5, bfLo(u5.y), b2); b3 = fmaf(w5, bfHi(u5.y), b3);
        a0 = fmaf(w6, bfLo(u6.x), a0); a1 = fmaf(w6, bfHi(u6.x), a1);
        a2 = fmaf(w6, bfLo(u6.y), a2); a3 = fmaf(w6, bfHi(u6.y), a3);
        b0 = fmaf(w7, bfLo(u7.x), b0); b1 = fmaf(w7, bfHi(u7.x), b1);
        b2 = fmaf(w7, bfLo(u7.y), b2); b3 = fmaf(w7, bfHi(u7.y), b3);
    }
    for (; j < e1; ++j) {
        unsigned v = csr[j];
        uint2 u = gin2[(size_t)(v & SRCMASK) * 10 + grel];
        float w = wUnpack(v);
        a0 = fmaf(w, bfLo(u.x), a0); a1 = fmaf(w, bfHi(u.x), a1);
        a2 = fmaf(w, bfLo(u.y), a2); a3 = fmaf(w, bfHi(u.y), a3);
    }
    if (act) {
        float dn = dis[node];
        float f0 = dn * (a0 + b0), f1 = dn * (a1 + b1);
        float f2 = dn * (a2 + b2), f3 = dn * (a3 + b3);
        uint2 o;
        o.x = (unsigned)f2bf(f0) | ((unsigned)f2bf(f1) << 16);
        o.y = (unsigned)f2bf(f2) | ((unsigned)f2bf(f3) << 16);
        ((uint2*)gout)[(size_t)node * 10 + grel] = o;
    }
}

// ---- conv2 + log_softmax epilogue; 10 lanes/node ----
__global__ __launch_bounds__(256) void spmv_final_kernel(
        const unsigned* __restrict__ g1, const unsigned* __restrict__ y,
        const float* __restrict__ bias, const int* __restrict__ start,
        const unsigned* __restrict__ csr, const float* __restrict__ dis,
        float* __restrict__ out, int N) {
    int lane = threadIdx.x & 63;
    int wid  = threadIdx.x >> 6;
    int grp  = lane / 10;
    int grel = lane - grp * 10;
    int node = blockIdx.x * 24 + wid * 6 + grp;
    bool act = (grp < 6) && (node < N);

    int e0 = 0, e1 = 0;
    if (act) { e0 = start[node]; e1 = start[node + 1]; }
    const uint2* g12 = (const uint2*)g1;

    float a0 = 0, a1 = 0, a2 = 0, a3 = 0;
    float b0 = 0, b1 = 0, b2 = 0, b3 = 0;
    int j = e0;
    for (; j + 7 < e1; j += 8) {
        unsigned v0 = csr[j],     v1 = csr[j + 1], v2 = csr[j + 2], v3 = csr[j + 3];
        unsigned v4 = csr[j + 4], v5 = csr[j + 5], v6 = csr[j + 6], v7 = csr[j + 7];
        uint2 u0 = g12[(size_t)(v0 & SRCMASK) * 10 + grel];
        uint2 u1 = g12[(size_t)(v1 & SRCMASK) * 10 + grel];
        uint2 u2 = g12[(size_t)(v2 & SRCMASK) * 10 + grel];
        uint2 u3 = g12[(size_t)(v3 & SRCMASK) * 10 + grel];
        uint2 u4 = g12[(size_t)(v4 & SRCMASK) * 10 + grel];
        uint2 u5 = g12[(size_t)(v5 & SRCMASK) * 10 + grel];
        uint2 u6 = g12[(size_t)(v6 & SRCMASK) * 10 + grel];
        uint2 u7 = g12[(size_t)(v7 & SRCMASK) * 10 + grel];
        float w0 = wUnpack(v0), w1 = wUnpack(v1), w2 = wUnpack(v2), w3 = wUnpack(v3);
        float w4 = wUnpack(v4), w5 = wUnpack(v5), w6 = wUnpack(v6), w7 = wUnpack(v7);
        a0 = fmaf(w0, bfLo(u0.x), a0); a1 = fmaf(w0, bfHi(u0.x), a1);
        a2 = fmaf(w0, bfLo(u0.y), a2); a3 = fmaf(w0, bfHi(u0.y), a3);
        b0 = fmaf(w1, bfLo(u1.x), b0); b1 = fmaf(w1, bfHi(u1.x), b1);
        b2 = fmaf(w1, bfLo(u1.y), b2); b3 = fmaf(w1, bfHi(u1.y), b3);
        a0 = fmaf(w2, bfLo(u2.x), a0); a1 = fmaf(w2, bfHi(u2.x), a1);
        a2 = fmaf(w2, bfLo(u2.y), a2); a3 = fmaf(w2, bfHi(u2.y), a3);
        b0 = fmaf(w3, bfLo(u3.x), b0); b1 = fmaf(w3, bfHi(u3.x), b1);
        b2 = fmaf(w3, bfLo(u3.y), b2); b3 = fmaf(w3, bfHi(u3.y), b3);
        a0 = fmaf(w4, bfLo(u4.x), a0); a1 = fmaf(w4, bfHi(u4.x), a1);
        a2 = fmaf(w4, bfLo(u4.y), a2); a3 = fmaf(w4, bfHi(u4.y), a3);
        b0 = fmaf(w5, bfLo(u5.x), b0); b1 = fmaf(w5, bfHi(u5.x), b1);
        b2 = fmaf(w5, bfLo(u5.y), b2); b3 = fmaf(w5, bfHi(u5.y), b3);
        a0 = fmaf(w6, bfLo(u6.x), a0); a1 = fmaf(w6, bfHi(u6.x), a1);
        a2 = fmaf(w6, bfLo(u6.y), a2); a3 = fmaf(w6, bfHi(u6.y), a3);
        b0 = fmaf(w7, bfLo(u7.x), b0); b1 = fmaf(w7, bfHi(u7.x), b1);
        b2 = fmaf(w7, bfLo(u7.y), b2); b3 = fmaf(w7, bfHi(u7.y), b3);
    }
    for (; j < e1; ++j) {
        unsigned v = csr[j];
        uint2 u = g12[(size_t)(v & SRCMASK) * 10 + grel];
        float w = wUnpack(v);
        a0 = fmaf(w, bfLo(u.x), a0); a1 = fmaf(w, bfHi(u.x), a1);
        a2 = fmaf(w, bfLo(u.y), a2); a3 = fmaf(w, bfHi(u.y), a3);
    }

    float l0 = 0, l1 = 0, l2 = 0, l3 = 0;
    if (act) {
        float dn = dis[node];
        float g20 = dn * (a0 + b0), g21 = dn * (a1 + b1);
        float g22 = dn * (a2 + b2), g23 = dn * (a3 + b3);
        uint2 yu = ((const uint2*)y)[(size_t)node * 10 + grel];
        uint2 gu = g12[(size_t)node * 10 + grel];
        float4 bv = *(const float4*)&bias[4 * grel];
        l0 = fmaf(ALPHA, bfLo(yu.x), fmaf(SCALE, bfLo(gu.x) + g20, bv.x));
        l1 = fmaf(ALPHA, bfHi(yu.x), fmaf(SCALE, bfHi(gu.x) + g21, bv.y));
        l2 = fmaf(ALPHA, bfLo(yu.y), fmaf(SCALE, bfLo(gu.y) + g22, bv.z));
        l3 = fmaf(ALPHA, bfHi(yu.y), fmaf(SCALE, bfHi(gu.y) + g23, bv.w));
    }

    float m = act ? fmaxf(fmaxf(l0, l1), fmaxf(l2, l3)) : -INFINITY;
    #pragma unroll
    for (int off = 8; off; off >>= 1) {
        float o = __shfl(m, lane + off);
        if (grel + off < 10) m = fmaxf(m, o);
    }
    m = __shfl(m, grp * 10);

    float ex = act ? (expf(l0 - m) + expf(l1 - m) + expf(l2 - m) + expf(l3 - m)) : 0.0f;
    #pragma unroll
    for (int off = 8; off; off >>= 1) {
        float o = __shfl(ex, lane + off);
        if (grel + off < 10) ex += o;
    }
    ex = __shfl(ex, grp * 10);

    if (act) {
        float lse = m + logf(ex);
        float2 oA, oB;
        oA.x = l0 - lse; oA.y = l1 - lse;
        oB.x = l2 - lse; oB.y = l3 - lse;
        double dA, dB;
        memcpy(&dA, &oA, 8);
        memcpy(&dB, &oB, 8);
        double* p = (double*)&out[(size_t)node * CDIM + 4 * grel];
        __builtin_nontemporal_store(dA, p);
        __builtin_nontemporal_store(dB, p + 1);
    }
}

extern "C" void kernel_launch(void* const* d_in, const int* in_sizes, int n_in,
                              void* d_out, int out_size, void* d_ws, size_t ws_size,
                              hipStream_t stream) {
    const float* x  = (const float*)d_in[0];   // [N,64]
    const float* ea = (const float*)d_in[1];   // [E]
    const float* W  = (const float*)d_in[2];   // [64,40]
    const float* b  = (const float*)d_in[3];   // [40]
    const int*   ei = (const int*)d_in[4];     // [2,E]: row then col

    const int N = in_sizes[0] / FDIM;
    const int E = in_sizes[1];
    const int* row = ei;
    const int* col = ei + E;

    const int NBLK = (E + CHUNK - 1) / CHUNK;

    // workspace layout (4-byte words; every used region fully written each call)
    int*   startp = (int*)d_ws;                   // NPAD
    float* dis    = (float*)(startp + NPAD);      // NPAD
    int*   alloc  = (int*)(dis + NPAD);           // 1024 (256 used)
    int2*  ppay   = (int2*)(alloc + 1024);        // 256*BCAP int2 (~21 MB)
    unsigned* csr = (unsigned*)(ppay + 256 * BCAP); // E packed dwords
    unsigned* g1bf = csr + E;                     // N*20
    unsigned* ybf  = (unsigned*)ppay;             // aliases ppay (dead after bucket_csr)

    hipMemsetAsync(alloc, 0, 256 * sizeof(int), stream);

    part_scatter<<<NBLK, 1024, 0, stream>>>(row, col, ea, alloc, ppay, E);
    bucket_csr  <<<256, 256, 0, stream>>>(ppay, alloc, startp, csr, dis, N);
    csr_scale_kernel<<<2048, 256, 0, stream>>>(csr, dis, E);
    lin_kernel  <<<(N + 63) / 64, 256, 0, stream>>>(x, W, ybf, N);

    int spmv_blocks = (N + 23) / 24;
    spmv_kernel      <<<spmv_blocks, 256, 0, stream>>>(ybf, startp, csr, dis, g1bf, N);
    spmv_final_kernel<<<spmv_blocks, 256, 0, stream>>>(g1bf, ybf, b, startp, csr, dis,
                                                       (float*)d_out, N);
}